// Round 1
// baseline (174.627 us; speedup 1.0000x reference)
//
#include <hip/hip_runtime.h>

// Problem constants (fixed by setup_inputs): B=4,T=32,H=224,W=224,C=3
namespace {
constexpr int B_ = 4, T_ = 32, H_ = 224, W_ = 224;
constexpr int HW_ = H_ * W_;              // 50176
constexpr int NPIX_ = B_ * T_ * HW_;      // 6422528
constexpr int N1_ = 79;                   // int(6422528*0.2*0.8 // 13005)
constexpr int N2_ = 9;                    // int(6422528*0.2*0.1 // 13005)
constexpr int NBOX_RW_ = N1_ + N2_;       // 88 boxes affect pixel output
constexpr int NBOX_M_  = N1_ + 2 * N2_;   // 97 boxes affect M
constexpr int HALF_T = 2, HALF_HW = 25;
}

// Kernel A: per (b,t) slice, collect the (h,w) rectangles that apply.
// rects[s][0..c1)      = R1 rects (mask_token)
// rects[s][N1..N1+c2)  = R2 rects (random_token, wins on overlap)
// Also writes M (any of 97 boxes touches slice) and gathers random_token.
__global__ void build_slice_rects(
    const float* __restrict__ frames,
    const int* __restrict__ bb, const int* __restrict__ tt,
    const int* __restrict__ hh, const int* __restrict__ ww,
    const int* __restrict__ rb, const int* __restrict__ rt,
    const int* __restrict__ rh, const int* __restrict__ rw,
    int2* __restrict__ counts, int4* __restrict__ rects,
    float* __restrict__ rtok, float* __restrict__ Mout)
{
    int s = threadIdx.x;
    if (s == 0) {
        long idx = (((long)rb[0] * T_ + rt[0]) * H_ + rh[0]) * W_ + rw[0];
        rtok[0] = frames[idx * 3 + 0];
        rtok[1] = frames[idx * 3 + 1];
        rtok[2] = frames[idx * 3 + 2];
    }
    if (s >= B_ * T_) return;
    int sb = s / T_, st = s % T_;
    int c1 = 0, c2 = 0;
    bool any = false;
    for (int i = 0; i < NBOX_M_; ++i) {
        int tlo = max(tt[i] - HALF_T, 0);
        int thi = min(tt[i] + HALF_T, T_ - 1);   // exclusive upper, ref uses size-1
        if (bb[i] != sb || st < tlo || st >= thi) continue;
        any = true;
        if (i >= NBOX_RW_) continue;             // R3: M only
        int4 r;
        r.x = max(hh[i] - HALF_HW, 0);
        r.y = min(hh[i] + HALF_HW, H_ - 1);      // exclusive
        r.z = max(ww[i] - HALF_HW, 0);
        r.w = min(ww[i] + HALF_HW, W_ - 1);      // exclusive
        if (i < N1_) rects[s * NBOX_RW_ + c1++] = r;
        else         rects[s * NBOX_RW_ + N1_ + c2++] = r;
    }
    counts[s] = make_int2(c1, c2);
    Mout[s] = any ? 1.0f : 0.0f;
}

// Kernel B: one thread per 4 pixels (12 floats = 3x float4, 16B-aligned since
// 4*3*4 = 48B groups). W=224 % 4 == 0 and p0 % 4 == 0 => all 4 pixels share
// the same (slice,row); only w varies (w0..w0+3).
__global__ __launch_bounds__(256) void apply_mask(
    const float* __restrict__ frames, const float* __restrict__ mtok,
    const int2* __restrict__ counts, const int4* __restrict__ rects,
    const float* __restrict__ rtok, float* __restrict__ out)
{
    int gid = blockIdx.x * blockDim.x + threadIdx.x;
    int p0 = gid * 4;
    if (p0 >= NPIX_) return;

    const float4* fin = (const float4*)(frames + (long)p0 * 3);
    float4 f0 = fin[0], f1 = fin[1], f2 = fin[2];

    int s  = p0 / HW_;
    int hw = p0 - s * HW_;
    int h  = hw / W_;
    int w0 = hw - h * W_;

    int2 c = counts[s];
    const int4* rs = rects + s * NBOX_RW_;
    int st0 = 0, st1 = 0, st2 = 0, st3 = 0;
    for (int j = 0; j < c.x; ++j) {          // R1: mask_token
        int4 r = rs[j];
        if (h >= r.x && h < r.y) {
            if (w0     >= r.z && w0     < r.w) st0 = 1;
            if (w0 + 1 >= r.z && w0 + 1 < r.w) st1 = 1;
            if (w0 + 2 >= r.z && w0 + 2 < r.w) st2 = 1;
            if (w0 + 3 >= r.z && w0 + 3 < r.w) st3 = 1;
        }
    }
    for (int j = 0; j < c.y; ++j) {          // R2: random_token, wins
        int4 r = rs[N1_ + j];
        if (h >= r.x && h < r.y) {
            if (w0     >= r.z && w0     < r.w) st0 = 2;
            if (w0 + 1 >= r.z && w0 + 1 < r.w) st1 = 2;
            if (w0 + 2 >= r.z && w0 + 2 < r.w) st2 = 2;
            if (w0 + 3 >= r.z && w0 + 3 < r.w) st3 = 2;
        }
    }

    float m0 = mtok[0], m1 = mtok[1], m2 = mtok[2];
    float r0 = rtok[0], r1 = rtok[1], r2 = rtok[2];

    float v[12] = {f0.x, f0.y, f0.z, f0.w, f1.x, f1.y, f1.z, f1.w,
                   f2.x, f2.y, f2.z, f2.w};
    int stk[4] = {st0, st1, st2, st3};
#pragma unroll
    for (int k = 0; k < 4; ++k) {
        int state = stk[k];
        v[k * 3 + 0] = (state == 2) ? r0 : ((state == 1) ? m0 : v[k * 3 + 0]);
        v[k * 3 + 1] = (state == 2) ? r1 : ((state == 1) ? m1 : v[k * 3 + 1]);
        v[k * 3 + 2] = (state == 2) ? r2 : ((state == 1) ? m2 : v[k * 3 + 2]);
    }

    float4* fo = (float4*)(out + (long)p0 * 3);
    fo[0] = make_float4(v[0], v[1], v[2], v[3]);
    fo[1] = make_float4(v[4], v[5], v[6], v[7]);
    fo[2] = make_float4(v[8], v[9], v[10], v[11]);
}

extern "C" void kernel_launch(void* const* d_in, const int* in_sizes, int n_in,
                              void* d_out, int out_size, void* d_ws, size_t ws_size,
                              hipStream_t stream)
{
    const float* frames = (const float*)d_in[0];
    const float* mtok   = (const float*)d_in[1];
    const int* b  = (const int*)d_in[2];
    const int* t  = (const int*)d_in[3];
    const int* h  = (const int*)d_in[4];
    const int* w  = (const int*)d_in[5];
    const int* rb = (const int*)d_in[6];
    const int* rt = (const int*)d_in[7];
    const int* rh = (const int*)d_in[8];
    const int* rw = (const int*)d_in[9];

    // ws layout: counts int2[128] (1KB) | rects int4[128][88] (176KB) | rtok f32[3]
    int2*  counts = (int2*)d_ws;
    int4*  rects  = (int4*)((char*)d_ws + 1024);
    float* rtok   = (float*)((char*)d_ws + 1024 + (size_t)128 * NBOX_RW_ * 16);

    float* out_frames = (float*)d_out;
    float* out_M      = out_frames + (long)NPIX_ * 3;   // (B,T) flags as 0/1 floats

    build_slice_rects<<<1, 128, 0, stream>>>(frames, b, t, h, w, rb, rt, rh, rw,
                                             counts, rects, rtok, out_M);

    int nthreads = NPIX_ / 4;                 // 1605632, divisible by 256
    apply_mask<<<nthreads / 256, 256, 0, stream>>>(frames, mtok, counts, rects,
                                                   rtok, out_frames);
}